// Round 3
// baseline (1314.523 us; speedup 1.0000x reference)
//
#include <hip/hip_runtime.h>

#define B 8
#define C 256
#define NN 4096

typedef float f32x4 __attribute__((ext_vector_type(4)));
typedef short s16x8 __attribute__((ext_vector_type(8)));
typedef unsigned short u16;
typedef unsigned int u32;

__device__ __forceinline__ u16 f2bf(float f) {
    u32 u = __builtin_bit_cast(u32, f);
    u32 r = (u + 0x7fffu + ((u >> 16) & 1u)) >> 16;
    return (u16)r;
}
__device__ __forceinline__ float bf2f(u16 h) {
    u32 u = ((u32)h) << 16;
    return __builtin_bit_cast(float, u);
}

#define MFMA(a, b, c) __builtin_amdgcn_mfma_f32_16x16x32_bf16((a), (b), (c), 0, 0, 0)

__device__ __forceinline__ f32x4 score_mfma(s16x8 akh, s16x8 akl, s16x8 bqh, s16x8 bql) {
    f32x4 s = {0.f, 0.f, 0.f, 0.f};
    s = MFMA(akh, bql, s);
    s = MFMA(akl, bqh, s);
    s = MFMA(akh, bqh, s);
    return s;
}

__global__ void k_sentinel(float* __restrict__ out, float v) { out[0] = v; }
__global__ void k_zero(u32* __restrict__ p) { *p = 0u; }

// ============ Self-test 1: QK hi/lo 3-MFMA pattern vs scalar =============
__global__ __launch_bounds__(64) void k_st1(u32* __restrict__ flags) {
    __shared__ float kf[16][32];
    __shared__ float qf[16][32];
    int l = threadIdx.x & 63;
    int lan = l & 15, g = l >> 4;
    if (threadIdx.x < 16) {
        int i = threadIdx.x;
        for (int d = 0; d < 32; d++) {
            kf[i][d] = 0.25f * (float)(((i * 131 + d * 29) % 17) - 8) + 0.00390625f * (float)((i + d) % 3);
            qf[i][d] = 0.25f * (float)(((i * 67 + d * 113) % 19) - 9) + 0.00390625f * (float)((i * d) % 5);
        }
    }
    __syncthreads();
    s16x8 akh, akl, bqh, bql;
#pragma unroll
    for (int e = 0; e < 8; e++) {
        float kv = kf[lan][g * 8 + e];
        u16 khi = f2bf(kv); u16 klo = f2bf(kv - bf2f(khi));
        akh[e] = (short)khi; akl[e] = (short)klo;
        float qv = qf[lan][g * 8 + e];
        u16 qhi = f2bf(qv); u16 qlo = f2bf(qv - bf2f(qhi));
        bqh[e] = (short)qhi; bql[e] = (short)qlo;
    }
    f32x4 s = score_mfma(akh, akl, bqh, bql);
#pragma unroll
    for (int r = 0; r < 4; r++) {
        float ref = 0.f;
        for (int d = 0; d < 32; d++) ref += kf[g * 4 + r][d] * qf[lan][d];
        if (fabsf(s[r] - ref) > 0.02f * (1.0f + fabsf(ref))) atomicOr(flags, 1u);
    }
}

// ====== Self-test 2: smat transpose-write + PV MFMA pattern vs scalar ======
__global__ __launch_bounds__(64) void k_st2(u32* __restrict__ flags) {
    __shared__ u16 smv[16 * 72]; // V[c][m], c 0..15, m 0..63
    __shared__ u16 smw[16 * 72]; // A^T [n][m], n 0..15, m 0..63
    int l = threadIdx.x & 63;
    int lan = l & 15, g = l >> 4;
    if (threadIdx.x < 16) {
        int c = threadIdx.x;
        for (int m = 0; m < 64; m++)
            smv[c * 72 + m] = f2bf(0.5f * (float)(((c * 37 + m * 11) % 13) - 6));
    }
    // replicate k_attn2's A write pattern: lane (lan,g) writes m = g + 4*j, row n=lan
    for (int j = 0; j < 16; j++) {
        int m = g + 4 * j;
        smw[lan * 72 + m] = f2bf(0.25f * (float)(((m * 23 + lan * 7) % 11) - 5));
    }
    __syncthreads();
    f32x4 acc = {0.f, 0.f, 0.f, 0.f};
#pragma unroll
    for (int ks = 0; ks < 2; ks++) {
        s16x8 bfrag = *(const s16x8*)&smw[lan * 72 + ks * 32 + g * 8];
        s16x8 afrag = *(const s16x8*)&smv[lan * 72 + ks * 32 + g * 8];
        acc = MFMA(afrag, bfrag, acc);
    }
#pragma unroll
    for (int r = 0; r < 4; r++) {
        int c = g * 4 + r, n = lan;
        float ref = 0.f;
        for (int m = 0; m < 64; m++) ref += bf2f(smv[c * 72 + m]) * bf2f(smw[n * 72 + m]);
        if (fabsf(acc[r] - ref) > 0.02f * (1.0f + fabsf(ref))) atomicOr(flags, 2u);
    }
}

__global__ void k_flag(const u32* __restrict__ flags, float* __restrict__ out) {
    u32 f = *flags;
    if (f) out[0] = 1.0e7f * (float)(2 + f);
}

// ============ q,k projections, pure fp32, thread-per-output ============
__global__ __launch_bounds__(256) void k_proj_qk_f32(
    const float* __restrict__ x, const float* __restrict__ wq, const float* __restrict__ bq,
    const float* __restrict__ wk, const float* __restrict__ bk,
    float* __restrict__ qT, float* __restrict__ kT)
{
    int flat = blockIdx.x * 256 + threadIdx.x; // 4096 blocks
    int d = flat & 31;
    int n = (flat >> 5) & 4095;
    int b = flat >> 17;
    float aq = bq[d], ak = bk[d];
    const float* xp = x + ((size_t)b * C) * NN + n;
    const float* wqr = wq + d * C;
    const float* wkr = wk + d * C;
    for (int c = 0; c < C; c++) {
        float xv = xp[(size_t)c * NN];
        aq += wqr[c] * xv;
        ak += wkr[c] * xv;
    }
    qT[((size_t)b * NN + n) * 32 + d] = aq;
    kT[((size_t)b * NN + n) * 32 + d] = ak;
}

// ============ v projection, fp32 tiled, output bf16 [B][C][N] ============
__global__ __launch_bounds__(256) void k_proj_v_f32(
    const float* __restrict__ x, const float* __restrict__ wv, const float* __restrict__ bv,
    u16* __restrict__ vbf)
{
    __shared__ float xs[64][68];
    __shared__ float wvs[64][68];
    int t = threadIdx.x;
    int n0 = blockIdx.x * 64;
    int e0 = blockIdx.y * 64;
    int b = blockIdx.z;
    int el0 = (t >> 4) * 4;
    int nl0 = (t & 15) * 4;
    float acc[4][4];
#pragma unroll
    for (int i = 0; i < 4; i++)
#pragma unroll
        for (int j = 0; j < 4; j++) acc[i][j] = 0.f;

    for (int cc = 0; cc < 4; cc++) {
        __syncthreads();
#pragma unroll
        for (int j = 0; j < 4; j++) {
            int idx4 = t + j * 256;
            int r = idx4 >> 4, c4 = (idx4 & 15) * 4;
            *(f32x4*)&xs[r][c4] = *(const f32x4*)&x[((size_t)b * C + cc * 64 + r) * NN + n0 + c4];
            *(f32x4*)&wvs[r][c4] = *(const f32x4*)&wv[(size_t)(e0 + r) * C + cc * 64 + c4];
        }
        __syncthreads();
        for (int c = 0; c < 64; c++) {
            float a0 = wvs[el0 + 0][c], a1 = wvs[el0 + 1][c], a2 = wvs[el0 + 2][c], a3 = wvs[el0 + 3][c];
            float b0 = xs[c][nl0 + 0], b1 = xs[c][nl0 + 1], b2 = xs[c][nl0 + 2], b3 = xs[c][nl0 + 3];
            acc[0][0] += a0 * b0; acc[0][1] += a0 * b1; acc[0][2] += a0 * b2; acc[0][3] += a0 * b3;
            acc[1][0] += a1 * b0; acc[1][1] += a1 * b1; acc[1][2] += a1 * b2; acc[1][3] += a1 * b3;
            acc[2][0] += a2 * b0; acc[2][1] += a2 * b1; acc[2][2] += a2 * b2; acc[2][3] += a2 * b3;
            acc[3][0] += a3 * b0; acc[3][1] += a3 * b1; acc[3][2] += a3 * b2; acc[3][3] += a3 * b3;
        }
    }
#pragma unroll
    for (int i = 0; i < 4; i++) {
        float bve = bv[e0 + el0 + i];
        ushort4 pk;
        pk.x = f2bf(acc[i][0] + bve);
        pk.y = f2bf(acc[i][1] + bve);
        pk.z = f2bf(acc[i][2] + bve);
        pk.w = f2bf(acc[i][3] + bve);
        *(ushort4*)&vbf[((size_t)b * C + e0 + el0 + i) * NN + n0 + nl0] = pk;
    }
}

// ============ Z sums (no max-subtract; scores are O(30), safe in fp32) ============
__global__ __launch_bounds__(256) void k_zsum(
    const float* __restrict__ qT, const float* __restrict__ kT,
    float* __restrict__ zinv)
{
    __shared__ float qs[128][32];
    __shared__ float lZp[4][64];
    int t = threadIdx.x;
    int w = t >> 6, l = t & 63;
    int m0 = blockIdx.x * 64, b = blockIdx.y;

    float kr[32];
    {
        size_t base = ((size_t)b * NN + m0 + l) * 32;
#pragma unroll
        for (int u = 0; u < 8; u++) {
            f32x4 v = *(const f32x4*)&kT[base + u * 4];
            kr[u * 4 + 0] = v[0]; kr[u * 4 + 1] = v[1]; kr[u * 4 + 2] = v[2]; kr[u * 4 + 3] = v[3];
        }
    }
    float zacc = 0.f;
    for (int ch = 0; ch < 32; ch++) {
        __syncthreads();
#pragma unroll
        for (int j = 0; j < 4; j++) {
            int idx4 = t + j * 256;
            int nn2 = idx4 >> 3, d4 = (idx4 & 7) * 4;
            *(f32x4*)&qs[nn2][d4] = *(const f32x4*)&qT[((size_t)b * NN + ch * 128 + nn2) * 32 + d4];
        }
        __syncthreads();
        for (int nn2 = 0; nn2 < 32; nn2++) {
            int nq = w * 32 + nn2;
            float s = 0.f;
#pragma unroll
            for (int u = 0; u < 8; u++) {
                f32x4 q4 = *(const f32x4*)&qs[nq][u * 4];
                s += kr[u * 4 + 0] * q4[0] + kr[u * 4 + 1] * q4[1] + kr[u * 4 + 2] * q4[2] + kr[u * 4 + 3] * q4[3];
            }
            zacc += __expf(s);
        }
    }
    lZp[w][l] = zacc;
    __syncthreads();
    if (t < 64) {
        float Z = lZp[0][t] + lZp[1][t] + lZp[2][t] + lZp[3][t];
        zinv[(size_t)b * NN + m0 + t] = 1.0f / Z;
    }
}

// ============ fp32 scores + A write + PV (MFMA) + epilogue ============
__global__ __launch_bounds__(256) void k_attn2(
    const float* __restrict__ x,
    const float* __restrict__ qT, const float* __restrict__ kT,
    const u16* __restrict__ vbf, const float* __restrict__ zinv,
    const float* __restrict__ gamma,
    float* __restrict__ out, float* __restrict__ amap)
{
    __shared__ u16 smv[256 * 72];     // V tile [256 c][72 pad], 64 m used
    __shared__ u16 smat[4 * 16 * 72]; // per-wave A^T [16 n][72 pad], 64 m used
    __shared__ float ks[64][36];      // K tile fp32
    int t = threadIdx.x;
    int w = t >> 6, l = t & 63;
    int lan = l & 15, g = l >> 4;
    int n0 = blockIdx.x * 64, b = blockIdx.y;
    int ncol = n0 + w * 16 + lan;

    float qr[32];
    {
        size_t base = ((size_t)b * NN + ncol) * 32;
#pragma unroll
        for (int u = 0; u < 8; u++) {
            f32x4 v = *(const f32x4*)&qT[base + u * 4];
            qr[u * 4 + 0] = v[0]; qr[u * 4 + 1] = v[1]; qr[u * 4 + 2] = v[2]; qr[u * 4 + 3] = v[3];
        }
    }
    f32x4 acc[16];
#pragma unroll
    for (int cs = 0; cs < 16; cs++) acc[cs] = {0.f, 0.f, 0.f, 0.f};
    u16* smw = smat + w * 16 * 72;

    for (int mstep = 0; mstep < 64; mstep++) {
        int m0 = mstep * 64;
        __syncthreads();
        // stage V tile (bf16) and K tile (fp32)
#pragma unroll
        for (int p = 0; p < 8; p++) {
            int flat8 = t + p * 256;
            int c = flat8 >> 3, mo = (flat8 & 7) * 8;
            *(s16x8*)&smv[c * 72 + mo] = *(const s16x8*)&vbf[((size_t)b * C + c) * NN + m0 + mo];
        }
#pragma unroll
        for (int j = 0; j < 2; j++) {
            int idx4 = t + j * 256;
            int mr = idx4 >> 3, d4 = (idx4 & 7) * 4;
            *(f32x4*)&ks[mr][d4] = *(const f32x4*)&kT[((size_t)b * NN + m0 + mr) * 32 + d4];
        }
        __syncthreads();
        // fp32 scores for 16 m rows per lane; write A (fp32) + bf16 into smw
        for (int j = 0; j < 16; j++) {
            int ml = g + 4 * j;
            float s = 0.f;
#pragma unroll
            for (int u = 0; u < 8; u++) {
                f32x4 k4 = *(const f32x4*)&ks[ml][u * 4];
                s += k4[0] * qr[u * 4 + 0] + k4[1] * qr[u * 4 + 1] + k4[2] * qr[u * 4 + 2] + k4[3] * qr[u * 4 + 3];
            }
            float a = __expf(s) * zinv[(size_t)b * NN + m0 + ml];
            amap[((size_t)b * NN + m0 + ml) * NN + ncol] = a;
            smw[lan * 72 + ml] = f2bf(a);
        }
        // PV: acc[c-tile] += V[c][m] * A[m][n]
#pragma unroll
        for (int ks2 = 0; ks2 < 2; ks2++) {
            s16x8 bfrag = *(const s16x8*)&smw[lan * 72 + ks2 * 32 + g * 8];
#pragma unroll
            for (int cs = 0; cs < 16; cs++) {
                s16x8 afrag = *(const s16x8*)&smv[(cs * 16 + lan) * 72 + ks2 * 32 + g * 8];
                acc[cs] = MFMA(afrag, bfrag, acc[cs]);
            }
        }
    }
    float gm = gamma[0];
#pragma unroll
    for (int cs = 0; cs < 16; cs++)
#pragma unroll
        for (int r = 0; r < 4; r++) {
            int c = cs * 16 + g * 4 + r;
            size_t oi = ((size_t)b * C + c) * NN + ncol;
            out[oi] = gm * acc[cs][r] + x[oi];
        }
}

extern "C" void kernel_launch(void* const* d_in, const int* in_sizes, int n_in,
                              void* d_out, int out_size, void* d_ws, size_t ws_size,
                              hipStream_t stream) {
    const float* x     = (const float*)d_in[0];
    const float* wq    = (const float*)d_in[1];
    const float* bq    = (const float*)d_in[2];
    const float* wk    = (const float*)d_in[3];
    const float* bk    = (const float*)d_in[4];
    const float* wv    = (const float*)d_in[5];
    const float* bv    = (const float*)d_in[6];
    const float* gamma = (const float*)d_in[7];
    float* out  = (float*)d_out;
    float* amap = out + (size_t)B * C * NN;

    const size_t WS_NEED = (size_t)26 << 20;
    if (ws_size < WS_NEED) {
        k_sentinel<<<dim3(1), dim3(1), 0, stream>>>(out, 8.0e7f);
        return;
    }
    if (n_in < 8 || in_sizes[0] != B * C * NN || in_sizes[1] != 32 * C ||
        in_sizes[2] != 32 || in_sizes[3] != 32 * C || in_sizes[4] != 32 ||
        in_sizes[5] != C * C || in_sizes[6] != C || in_sizes[7] != 1) {
        k_sentinel<<<dim3(1), dim3(1), 0, stream>>>(out, 9.0e7f);
        return;
    }

    unsigned char* ws = (unsigned char*)d_ws;
    float* qT   = (float*)(ws);
    float* kT   = (float*)(ws + ((size_t)4 << 20));
    u16*   vbf  = (u16*)(ws + ((size_t)8 << 20));
    float* zinv = (float*)(ws + ((size_t)24 << 20));
    u32*   flags = (u32*)(ws + ((size_t)24 << 20) + 0x40000);

    k_zero<<<dim3(1), dim3(1), 0, stream>>>(flags);
    k_st1<<<dim3(1), dim3(64), 0, stream>>>(flags);
    k_st2<<<dim3(1), dim3(64), 0, stream>>>(flags);
    k_proj_qk_f32<<<dim3(4096), dim3(256), 0, stream>>>(x, wq, bq, wk, bk, qT, kT);
    k_proj_v_f32<<<dim3(64, 4, 8), dim3(256), 0, stream>>>(x, wv, bv, vbf);
    k_zsum<<<dim3(64, 8), dim3(256), 0, stream>>>(qT, kT, zinv);
    k_attn2<<<dim3(64, 8), dim3(256), 0, stream>>>(x, qT, kT, vbf, zinv, gamma, out, amap);
    k_flag<<<dim3(1), dim3(1), 0, stream>>>(flags, out);
}

// Round 4
// 872.188 us; speedup vs baseline: 1.5072x; 1.5072x over previous
//
#include <hip/hip_runtime.h>

#define B 8
#define C 256
#define NN 4096

typedef float f32x4 __attribute__((ext_vector_type(4)));
typedef short s16x8 __attribute__((ext_vector_type(8)));
typedef unsigned short u16;
typedef unsigned int u32;

__device__ __forceinline__ u16 f2bf(float f) {
    u32 u = __builtin_bit_cast(u32, f);
    u32 r = (u + 0x7fffu + ((u >> 16) & 1u)) >> 16;
    return (u16)r;
}
__device__ __forceinline__ float bf2f(u16 h) {
    u32 u = ((u32)h) << 16;
    return __builtin_bit_cast(float, u);
}

#define MFMA(a, b, c) __builtin_amdgcn_mfma_f32_16x16x32_bf16((a), (b), (c), 0, 0, 0)

// Validated on-device (round-3 k_st1): A-frag lane(lan,g)=A[lan][g*8+e],
// B-frag lane(lan,g)=B[lan][g*8+e], D[r] = sum_d A[g*4+r][d]*B[lan][d].
__device__ __forceinline__ f32x4 score_mfma(s16x8 akh, s16x8 akl, s16x8 bqh, s16x8 bql) {
    f32x4 s = {0.f, 0.f, 0.f, 0.f};
    s = MFMA(akh, bql, s);
    s = MFMA(akl, bqh, s);
    s = MFMA(akh, bqh, s);
    return s;
}

__global__ void k_sentinel(float* __restrict__ out, float v) { out[0] = v; }

// ---------------- wv -> bf16 cast (elementwise) ----------------
__global__ void k_cast_wv(const float* __restrict__ wv, u16* __restrict__ wvb) {
    int i = blockIdx.x * 256 + threadIdx.x;
    wvb[i] = f2bf(wv[i]);
}

// ------- q,k projection, fp32 accum, in-register hi/lo split -> [B][N][32] -------
__global__ __launch_bounds__(256) void k_proj_qk(
    const float* __restrict__ x, const float* __restrict__ wq, const float* __restrict__ bq,
    const float* __restrict__ wk, const float* __restrict__ bk,
    u16* __restrict__ qh, u16* __restrict__ ql, u16* __restrict__ kh, u16* __restrict__ kl)
{
    int flat = blockIdx.x * 256 + threadIdx.x;
    int d = flat & 31;
    int n = (flat >> 5) & 4095;
    int b = flat >> 17;
    float aq = bq[d], ak = bk[d];
    const float* xp = x + ((size_t)b * C) * NN + n;
    const float* wqr = wq + d * C;
    const float* wkr = wk + d * C;
    for (int c = 0; c < C; c++) {
        float xv = xp[(size_t)c * NN];
        aq += wqr[c] * xv;
        ak += wkr[c] * xv;
    }
    size_t idx = ((size_t)b * NN + n) * 32 + d;
    u16 qhi = f2bf(aq); u16 qlo = f2bf(aq - bf2f(qhi));
    u16 khi = f2bf(ak); u16 klo = f2bf(ak - bf2f(khi));
    qh[idx] = qhi; ql[idx] = qlo;
    kh[idx] = khi; kl[idx] = klo;
}

// ------- v projection, bf16 MFMA (PV-validated fragment convention) -------
__global__ __launch_bounds__(256) void k_proj_v(
    const float* __restrict__ x, const u16* __restrict__ wvb, const float* __restrict__ bv,
    u16* __restrict__ vbf)
{
    __shared__ u16 smx[64 * 264]; // xT tile [64 n][264 c-pad]
    int t = threadIdx.x;
    int w = t >> 6, l = t & 63;
    int lan = l & 15, g = l >> 4;
    int b = blockIdx.x, nblk = blockIdx.y;
    int n0 = nblk * 64;
#pragma unroll
    for (int p = 0; p < 16; p++) {
        int flat4 = t + p * 256;
        int c = flat4 >> 4, n4 = (flat4 & 15) * 4;
        float4 xv = *(const float4*)&x[((size_t)b * C + c) * NN + n0 + n4];
        smx[(n4 + 0) * 264 + c] = f2bf(xv.x);
        smx[(n4 + 1) * 264 + c] = f2bf(xv.y);
        smx[(n4 + 2) * 264 + c] = f2bf(xv.z);
        smx[(n4 + 3) * 264 + c] = f2bf(xv.w);
    }
    __syncthreads();
    f32x4 acc[16];
#pragma unroll
    for (int es = 0; es < 16; es++) acc[es] = {0.f, 0.f, 0.f, 0.f};
    int nrow = w * 16 + lan;
    for (int ck = 0; ck < 8; ck++) {
        int c0 = ck * 32 + g * 8;
        s16x8 bfrag = *(const s16x8*)&smx[nrow * 264 + c0];
#pragma unroll
        for (int es = 0; es < 16; es++) {
            s16x8 afrag = *(const s16x8*)&wvb[(size_t)(es * 16 + lan) * 256 + c0];
            acc[es] = MFMA(afrag, bfrag, acc[es]);
        }
    }
    int ncol = n0 + w * 16 + lan;
#pragma unroll
    for (int es = 0; es < 16; es++)
#pragma unroll
        for (int r = 0; r < 4; r++) {
            int e = es * 16 + g * 4 + r;
            vbf[((size_t)b * C + e) * NN + ncol] = f2bf(acc[es][r] + bv[e]);
        }
}

// ------- phase 1: Z sums via MFMA scores (bit-identical S to k_attn2) -------
__global__ __launch_bounds__(256) void k_zsum(
    const u16* __restrict__ qh, const u16* __restrict__ ql,
    const u16* __restrict__ kh, const u16* __restrict__ kl,
    float* __restrict__ zinv)
{
    __shared__ float lZ[4][64];
    int t = threadIdx.x;
    int w = t >> 6, l = t & 63;
    int lan = l & 15, g = l >> 4;
    int b = blockIdx.x, mblk = blockIdx.y;
    int m0 = mblk * 64;

    s16x8 akh[4], akl[4];
#pragma unroll
    for (int ms = 0; ms < 4; ms++) {
        size_t ko = ((size_t)b * NN + m0 + ms * 16 + lan) * 32 + g * 8;
        akh[ms] = *(const s16x8*)&kh[ko];
        akl[ms] = *(const s16x8*)&kl[ko];
    }
    float zacc[4][4] = {};
    for (int ci = 0; ci < 64; ci++) {
        int nch = (ci * 4 + w) * 16; // interleaved chunks across waves
        size_t qo = ((size_t)b * NN + nch + lan) * 32 + g * 8;
        s16x8 bqh = *(const s16x8*)&qh[qo];
        s16x8 bql = *(const s16x8*)&ql[qo];
#pragma unroll
        for (int ms = 0; ms < 4; ms++) {
            f32x4 s = score_mfma(akh[ms], akl[ms], bqh, bql);
#pragma unroll
            for (int r = 0; r < 4; r++) zacc[ms][r] += __expf(s[r]);
        }
    }
#pragma unroll
    for (int ms = 0; ms < 4; ms++)
#pragma unroll
        for (int r = 0; r < 4; r++) {
            float v = zacc[ms][r];
#pragma unroll
            for (int off = 1; off < 16; off <<= 1) v += __shfl_xor(v, off);
            zacc[ms][r] = v;
        }
    if (lan == 0) {
#pragma unroll
        for (int ms = 0; ms < 4; ms++)
#pragma unroll
            for (int r = 0; r < 4; r++) lZ[w][ms * 16 + g * 4 + r] = zacc[ms][r];
    }
    __syncthreads();
    if (t < 64) {
        float Z = lZ[0][t] + lZ[1][t] + lZ[2][t] + lZ[3][t];
        zinv[(size_t)b * NN + m0 + t] = 1.0f / Z;
    }
}

// ------- phase 2: MFMA scores + A write + PV MFMA + epilogue -------
__global__ __launch_bounds__(256) void k_attn2(
    const float* __restrict__ x,
    const u16* __restrict__ qh, const u16* __restrict__ ql,
    const u16* __restrict__ kh, const u16* __restrict__ kl,
    const u16* __restrict__ vbf, const float* __restrict__ zinv,
    const float* __restrict__ gamma,
    float* __restrict__ out, float* __restrict__ amap)
{
    __shared__ u16 smv[256 * 72];     // V tile [256 c][72 pad], 64 m used
    __shared__ u16 smat[4 * 16 * 72]; // per-wave A^T [16 n][72 pad], 64 m used
    int t = threadIdx.x;
    int w = t >> 6, l = t & 63;
    int lan = l & 15, g = l >> 4;
    int b = blockIdx.x, nblk = blockIdx.y;
    int n0 = nblk * 64;
    int ncol = n0 + w * 16 + lan;

    size_t qo = ((size_t)b * NN + ncol) * 32 + g * 8;
    s16x8 bqh = *(const s16x8*)&qh[qo];
    s16x8 bql = *(const s16x8*)&ql[qo];

    f32x4 acc[16];
#pragma unroll
    for (int cs = 0; cs < 16; cs++) acc[cs] = {0.f, 0.f, 0.f, 0.f};
    u16* smw = smat + w * 16 * 72;

    for (int mstep = 0; mstep < 64; mstep++) {
        int m0 = mstep * 64;
        __syncthreads();
#pragma unroll
        for (int p = 0; p < 8; p++) {
            int flat8 = t + p * 256;
            int c = flat8 >> 3, mo = (flat8 & 7) * 8;
            *(s16x8*)&smv[c * 72 + mo] = *(const s16x8*)&vbf[((size_t)b * C + c) * NN + m0 + mo];
        }
        __syncthreads();
        // MFMA scores (validated pattern), A write (fp32 global + bf16 LDS)
#pragma unroll
        for (int ms = 0; ms < 4; ms++) {
            size_t ko = ((size_t)b * NN + m0 + ms * 16 + lan) * 32 + g * 8;
            s16x8 fkh = *(const s16x8*)&kh[ko];
            s16x8 fkl = *(const s16x8*)&kl[ko];
            f32x4 s = score_mfma(fkh, fkl, bqh, bql);
            float av[4];
#pragma unroll
            for (int r = 0; r < 4; r++) {
                int mrow = m0 + ms * 16 + g * 4 + r;
                float a = __expf(s[r]) * zinv[(size_t)b * NN + mrow];
                amap[((size_t)b * NN + mrow) * NN + ncol] = a;
                av[r] = a;
            }
            uint2 pk;
            pk.x = (u32)f2bf(av[0]) | ((u32)f2bf(av[1]) << 16);
            pk.y = (u32)f2bf(av[2]) | ((u32)f2bf(av[3]) << 16);
            *(uint2*)&smw[lan * 72 + ms * 16 + g * 4] = pk;
        }
        // PV: acc[c-tile] += V[c][m] * A[m][n]  (validated pattern)
#pragma unroll
        for (int ks2 = 0; ks2 < 2; ks2++) {
            s16x8 bfrag = *(const s16x8*)&smw[lan * 72 + ks2 * 32 + g * 8];
#pragma unroll
            for (int cs = 0; cs < 16; cs++) {
                s16x8 afrag = *(const s16x8*)&smv[(cs * 16 + lan) * 72 + ks2 * 32 + g * 8];
                acc[cs] = MFMA(afrag, bfrag, acc[cs]);
            }
        }
    }
    float gm = gamma[0];
#pragma unroll
    for (int cs = 0; cs < 16; cs++)
#pragma unroll
        for (int r = 0; r < 4; r++) {
            int c = cs * 16 + g * 4 + r;
            size_t oi = ((size_t)b * C + c) * NN + ncol;
            out[oi] = gm * acc[cs][r] + x[oi];
        }
}

extern "C" void kernel_launch(void* const* d_in, const int* in_sizes, int n_in,
                              void* d_out, int out_size, void* d_ws, size_t ws_size,
                              hipStream_t stream) {
    const float* x     = (const float*)d_in[0];
    const float* wq    = (const float*)d_in[1];
    const float* bq    = (const float*)d_in[2];
    const float* wk    = (const float*)d_in[3];
    const float* bk    = (const float*)d_in[4];
    const float* wv    = (const float*)d_in[5];
    const float* bv    = (const float*)d_in[6];
    const float* gamma = (const float*)d_in[7];
    float* out  = (float*)d_out;
    float* amap = out + (size_t)B * C * NN;

    const size_t WS_NEED = (size_t)26 << 20;
    if (ws_size < WS_NEED) {
        k_sentinel<<<dim3(1), dim3(1), 0, stream>>>(out, 8.0e7f);
        return;
    }
    if (n_in < 8 || in_sizes[0] != B * C * NN || in_sizes[1] != 32 * C ||
        in_sizes[2] != 32 || in_sizes[3] != 32 * C || in_sizes[4] != 32 ||
        in_sizes[5] != C * C || in_sizes[6] != C || in_sizes[7] != 1) {
        k_sentinel<<<dim3(1), dim3(1), 0, stream>>>(out, 9.0e7f);
        return;
    }

    unsigned char* ws = (unsigned char*)d_ws;
    u16* qh   = (u16*)(ws);
    u16* ql   = (u16*)(ws + ((size_t)2 << 20));
    u16* kh   = (u16*)(ws + ((size_t)4 << 20));
    u16* kl   = (u16*)(ws + ((size_t)6 << 20));
    u16* vbf  = (u16*)(ws + ((size_t)8 << 20));
    float* zinv = (float*)(ws + ((size_t)24 << 20));
    u16* wvb  = (u16*)(ws + ((size_t)24 << 20) + 0x40000);

    k_cast_wv<<<dim3(256), dim3(256), 0, stream>>>(wv, wvb);
    k_proj_qk<<<dim3(4096), dim3(256), 0, stream>>>(x, wq, bq, wk, bk, qh, ql, kh, kl);
    k_proj_v<<<dim3(8, 64), dim3(256), 0, stream>>>(x, wvb, bv, vbf);
    k_zsum<<<dim3(8, 64), dim3(256), 0, stream>>>(qh, ql, kh, kl, zinv);
    k_attn2<<<dim3(8, 64), dim3(256), 0, stream>>>(x, qh, ql, kh, kl, vbf, zinv, gamma, out, amap);
}

// Round 5
// 619.741 us; speedup vs baseline: 2.1211x; 1.4073x over previous
//
#include <hip/hip_runtime.h>

#define B 8
#define C 256
#define NN 4096

typedef float f32x4 __attribute__((ext_vector_type(4)));
typedef short s16x8 __attribute__((ext_vector_type(8)));
typedef unsigned short u16;
typedef unsigned int u32;

__device__ __forceinline__ u16 f2bf(float f) {
    u32 u = __builtin_bit_cast(u32, f);
    u32 r = (u + 0x7fffu + ((u >> 16) & 1u)) >> 16;
    return (u16)r;
}
__device__ __forceinline__ float bf2f(u16 h) {
    u32 u = ((u32)h) << 16;
    return __builtin_bit_cast(float, u);
}

#define MFMA(a, b, c) __builtin_amdgcn_mfma_f32_16x16x32_bf16((a), (b), (c), 0, 0, 0)

// Validated convention (k_st1): D[r]@(lan,g) = sum_d A[g*4+r][d] * B[lan][d].
// Transposed-score: A = Q (rows n), B = K (rows m) -> lane holds m = mbase+lan,
// rows r = 4 consecutive n. Used IDENTICALLY in k_zsum and k_attn2.
__device__ __forceinline__ f32x4 score_mfma_t(s16x8 aqh, s16x8 aql, s16x8 bkh, s16x8 bkl) {
    f32x4 s = {0.f, 0.f, 0.f, 0.f};
    s = MFMA(aqh, bkl, s);
    s = MFMA(aql, bkh, s);
    s = MFMA(aqh, bkh, s);
    return s;
}

__global__ void k_sentinel(float* __restrict__ out, float v) { out[0] = v; }

// ---------------- wv -> bf16 cast ----------------
__global__ void k_cast_wv(const float* __restrict__ wv, u16* __restrict__ wvb) {
    int i = blockIdx.x * 256 + threadIdx.x;
    wvb[i] = f2bf(wv[i]);
}

// ------- q,k projection: coalesced x, SMEM weights, LDS-transposed stores -------
__global__ __launch_bounds__(256) void k_proj_qk(
    const float* __restrict__ x, const float* __restrict__ wq, const float* __restrict__ bq,
    const float* __restrict__ wk, const float* __restrict__ bk,
    u16* __restrict__ qh, u16* __restrict__ ql, u16* __restrict__ kh, u16* __restrict__ kl)
{
    __shared__ u32 sq[64][36];
    __shared__ u32 sk[64][36];
    int t = threadIdx.x;
    int w = t >> 6, l = t & 63;
    int b = blockIdx.x, ng = blockIdx.y;
    int n0 = ng * 64;

    float aq[8], ak[8];
#pragma unroll
    for (int i = 0; i < 8; i++) { aq[i] = bq[w * 8 + i]; ak[i] = bk[w * 8 + i]; }

    const float* xp = x + (size_t)b * C * NN + n0 + l;
    for (int c = 0; c < C; c++) {
        float xv = xp[(size_t)c * NN];
#pragma unroll
        for (int i = 0; i < 8; i++) {
            aq[i] += wq[(w * 8 + i) * C + c] * xv;  // wave-uniform -> SMEM
            ak[i] += wk[(w * 8 + i) * C + c] * xv;
        }
    }
#pragma unroll
    for (int i = 0; i < 8; i++) {
        u16 qhi = f2bf(aq[i]); u16 qlo = f2bf(aq[i] - bf2f(qhi));
        u16 khi = f2bf(ak[i]); u16 klo = f2bf(ak[i] - bf2f(khi));
        sq[l][w * 8 + i] = ((u32)qhi << 16) | qlo;
        sk[l][w * 8 + i] = ((u32)khi << 16) | klo;
    }
    __syncthreads();
    // writeout: lane t -> row n=t>>2, d-chunk (t&3)*8; 16B per store, rows 64B contiguous
    int nloc = t >> 2, dc = t & 3;
    size_t base = ((size_t)b * NN + n0 + nloc) * 32 + dc * 8;
    uint4 a0 = *(const uint4*)&sq[nloc][dc * 8];
    uint4 a1 = *(const uint4*)&sq[nloc][dc * 8 + 4];
    uint4 b0 = *(const uint4*)&sk[nloc][dc * 8];
    uint4 b1 = *(const uint4*)&sk[nloc][dc * 8 + 4];
    s16x8 vqh, vql, vkh, vkl;
    u32 qa[8] = {a0.x, a0.y, a0.z, a0.w, a1.x, a1.y, a1.z, a1.w};
    u32 ka[8] = {b0.x, b0.y, b0.z, b0.w, b1.x, b1.y, b1.z, b1.w};
#pragma unroll
    for (int i = 0; i < 8; i++) {
        vqh[i] = (short)(qa[i] >> 16); vql[i] = (short)(qa[i] & 0xffff);
        vkh[i] = (short)(ka[i] >> 16); vkl[i] = (short)(ka[i] & 0xffff);
    }
    *(s16x8*)&qh[base] = vqh;
    *(s16x8*)&ql[base] = vql;
    *(s16x8*)&kh[base] = vkh;
    *(s16x8*)&kl[base] = vkl;
}

// ------- v projection, bf16 MFMA (validated convention, unchanged) -------
__global__ __launch_bounds__(256) void k_proj_v(
    const float* __restrict__ x, const u16* __restrict__ wvb, const float* __restrict__ bv,
    u16* __restrict__ vbf)
{
    __shared__ u16 smx[64 * 264];
    int t = threadIdx.x;
    int w = t >> 6, l = t & 63;
    int lan = l & 15, g = l >> 4;
    int b = blockIdx.x, nblk = blockIdx.y;
    int n0 = nblk * 64;
#pragma unroll
    for (int p = 0; p < 16; p++) {
        int flat4 = t + p * 256;
        int c = flat4 >> 4, n4 = (flat4 & 15) * 4;
        float4 xv = *(const float4*)&x[((size_t)b * C + c) * NN + n0 + n4];
        smx[(n4 + 0) * 264 + c] = f2bf(xv.x);
        smx[(n4 + 1) * 264 + c] = f2bf(xv.y);
        smx[(n4 + 2) * 264 + c] = f2bf(xv.z);
        smx[(n4 + 3) * 264 + c] = f2bf(xv.w);
    }
    __syncthreads();
    f32x4 acc[16];
#pragma unroll
    for (int es = 0; es < 16; es++) acc[es] = {0.f, 0.f, 0.f, 0.f};
    int nrow = w * 16 + lan;
    for (int ck = 0; ck < 8; ck++) {
        int c0 = ck * 32 + g * 8;
        s16x8 bfrag = *(const s16x8*)&smx[nrow * 264 + c0];
#pragma unroll
        for (int es = 0; es < 16; es++) {
            s16x8 afrag = *(const s16x8*)&wvb[(size_t)(es * 16 + lan) * 256 + c0];
            acc[es] = MFMA(afrag, bfrag, acc[es]);
        }
    }
    int ncol = n0 + w * 16 + lan;
#pragma unroll
    for (int es = 0; es < 16; es++)
#pragma unroll
        for (int r = 0; r < 4; r++) {
            int e = es * 16 + g * 4 + r;
            vbf[((size_t)b * C + e) * NN + ncol] = f2bf(acc[es][r] + bv[e]);
        }
}

// ------- phase 1: Z sums, transposed scores (lane-local m rows) -------
__global__ __launch_bounds__(256) void k_zsum(
    const u16* __restrict__ qh, const u16* __restrict__ ql,
    const u16* __restrict__ kh, const u16* __restrict__ kl,
    float* __restrict__ zinv)
{
    __shared__ float lZ[4][64];
    int t = threadIdx.x;
    int w = t >> 6, l = t & 63;
    int lan = l & 15, g = l >> 4;
    int b = blockIdx.x, mblk = blockIdx.y;
    int m0 = mblk * 64;

    s16x8 bkh[4], bkl[4];
#pragma unroll
    for (int ms = 0; ms < 4; ms++) {
        size_t ko = ((size_t)b * NN + m0 + ms * 16 + lan) * 32 + g * 8;
        bkh[ms] = *(const s16x8*)&kh[ko];
        bkl[ms] = *(const s16x8*)&kl[ko];
    }
    float zacc[4] = {0.f, 0.f, 0.f, 0.f};
    for (int ci = 0; ci < 64; ci++) {
        int nt = ci * 4 + w;
        size_t qo = ((size_t)b * NN + nt * 16 + lan) * 32 + g * 8;
        s16x8 aqh = *(const s16x8*)&qh[qo];
        s16x8 aql = *(const s16x8*)&ql[qo];
#pragma unroll
        for (int ms = 0; ms < 4; ms++) {
            f32x4 s = score_mfma_t(aqh, aql, bkh[ms], bkl[ms]);
            zacc[ms] += __expf(s[0]) + __expf(s[1]) + __expf(s[2]) + __expf(s[3]);
        }
    }
#pragma unroll
    for (int ms = 0; ms < 4; ms++) {
        float v = zacc[ms];
        v += __shfl_xor(v, 16);
        v += __shfl_xor(v, 32);
        zacc[ms] = v;
    }
    if (g == 0) {
#pragma unroll
        for (int ms = 0; ms < 4; ms++) lZ[w][ms * 16 + lan] = zacc[ms];
    }
    __syncthreads();
    if (t < 64) {
        float Z = lZ[0][t] + lZ[1][t] + lZ[2][t] + lZ[3][t];
        zinv[(size_t)b * NN + m0 + t] = 1.0f / Z;
    }
}

// ------- phase 2: transposed scores + dwordx4 A write + PV + epilogue -------
__global__ __launch_bounds__(256, 2) void k_attn2(
    const float* __restrict__ x,
    const u16* __restrict__ qh, const u16* __restrict__ ql,
    const u16* __restrict__ kh, const u16* __restrict__ kl,
    const u16* __restrict__ vbf, const float* __restrict__ zinv,
    const float* __restrict__ gamma,
    float* __restrict__ out, float* __restrict__ amap)
{
    __shared__ u16 smv[16384];        // V tile [256 c][64 m], chunk-XOR-swizzled
    __shared__ u16 smat[4][16 * 72];  // per-wave A^T [16 n][72 pad m]
    int t = threadIdx.x;
    int w = t >> 6, l = t & 63;
    int lan = l & 15, g = l >> 4;
    int b = blockIdx.x, nblk = blockIdx.y;
    int n0 = nblk * 64;
    int nw = n0 + w * 16;

    size_t qo = ((size_t)b * NN + nw + lan) * 32 + g * 8;
    s16x8 aqh = *(const s16x8*)&qh[qo];
    s16x8 aql = *(const s16x8*)&ql[qo];

    f32x4 acc[16];
#pragma unroll
    for (int cs = 0; cs < 16; cs++) acc[cs] = {0.f, 0.f, 0.f, 0.f};
    u16* smw = smat[w];
    const u16* vb = vbf + (size_t)b * C * NN;

    // prologue: stage V tile 0
    s16x8 vreg[8];
#pragma unroll
    for (int p = 0; p < 8; p++) {
        int f8 = t + p * 256; int c = f8 >> 3, j = f8 & 7;
        vreg[p] = *(const s16x8*)&vb[(size_t)c * NN + j * 8];
    }
#pragma unroll
    for (int p = 0; p < 8; p++) {
        int f8 = t + p * 256; int c = f8 >> 3, j = f8 & 7;
        *(s16x8*)&smv[c * 64 + ((j ^ (c & 7)) * 8)] = vreg[p];
    }
    __syncthreads();

    for (int mstep = 0; mstep < 64; mstep++) {
        int m0 = mstep * 64;
        // T14: issue next V tile's global loads now; write after the barrier
        if (mstep < 63) {
#pragma unroll
            for (int p = 0; p < 8; p++) {
                int f8 = t + p * 256; int c = f8 >> 3, j = f8 & 7;
                vreg[p] = *(const s16x8*)&vb[(size_t)c * NN + m0 + 64 + j * 8];
            }
        }
        // scores: lane owns m = m0+ms*16+lan, 4 consecutive n = nw+g*4+r
#pragma unroll
        for (int ms = 0; ms < 4; ms++) {
            size_t ko = ((size_t)b * NN + m0 + ms * 16 + lan) * 32 + g * 8;
            s16x8 fkh = *(const s16x8*)&kh[ko];
            s16x8 fkl = *(const s16x8*)&kl[ko];
            f32x4 s = score_mfma_t(aqh, aql, fkh, fkl);
            float zi = zinv[(size_t)b * NN + m0 + ms * 16 + lan];
            f32x4 av;
#pragma unroll
            for (int r = 0; r < 4; r++) av[r] = __expf(s[r]) * zi;
            *(f32x4*)&amap[((size_t)b * NN + m0 + ms * 16 + lan) * NN + nw + g * 4] = av;
#pragma unroll
            for (int r = 0; r < 4; r++)
                smw[(g * 4 + r) * 72 + ms * 16 + lan] = f2bf(av[r]);
        }
        // PV: acc[cs] (c = cs*16+g*4+r, n = nw+lan) += V[c][m] * A[m][n]
#pragma unroll
        for (int ks = 0; ks < 2; ks++) {
            s16x8 bfrag = *(const s16x8*)&smw[lan * 72 + ks * 32 + g * 8];
#pragma unroll
            for (int cs = 0; cs < 16; cs++) {
                int row = cs * 16 + lan;
                s16x8 afrag = *(const s16x8*)&smv[row * 64 + (((ks * 4 + g) ^ (lan & 7)) * 8)];
                acc[cs] = MFMA(afrag, bfrag, acc[cs]);
            }
        }
        __syncthreads();
        if (mstep < 63) {
#pragma unroll
            for (int p = 0; p < 8; p++) {
                int f8 = t + p * 256; int c = f8 >> 3, j = f8 & 7;
                *(s16x8*)&smv[c * 64 + ((j ^ (c & 7)) * 8)] = vreg[p];
            }
        }
        __syncthreads();
    }
    float gm = gamma[0];
    int ncol = nw + lan;
#pragma unroll
    for (int cs = 0; cs < 16; cs++)
#pragma unroll
        for (int r = 0; r < 4; r++) {
            int c = cs * 16 + g * 4 + r;
            size_t oi = ((size_t)b * C + c) * NN + ncol;
            out[oi] = gm * acc[cs][r] + x[oi];
        }
}

extern "C" void kernel_launch(void* const* d_in, const int* in_sizes, int n_in,
                              void* d_out, int out_size, void* d_ws, size_t ws_size,
                              hipStream_t stream) {
    const float* x     = (const float*)d_in[0];
    const float* wq    = (const float*)d_in[1];
    const float* bq    = (const float*)d_in[2];
    const float* wk    = (const float*)d_in[3];
    const float* bk    = (const float*)d_in[4];
    const float* wv    = (const float*)d_in[5];
    const float* bv    = (const float*)d_in[6];
    const float* gamma = (const float*)d_in[7];
    float* out  = (float*)d_out;
    float* amap = out + (size_t)B * C * NN;

    const size_t WS_NEED = (size_t)26 << 20;
    if (ws_size < WS_NEED) {
        k_sentinel<<<dim3(1), dim3(1), 0, stream>>>(out, 8.0e7f);
        return;
    }
    if (n_in < 8 || in_sizes[0] != B * C * NN || in_sizes[1] != 32 * C ||
        in_sizes[2] != 32 || in_sizes[3] != 32 * C || in_sizes[4] != 32 ||
        in_sizes[5] != C * C || in_sizes[6] != C || in_sizes[7] != 1) {
        k_sentinel<<<dim3(1), dim3(1), 0, stream>>>(out, 9.0e7f);
        return;
    }

    unsigned char* ws = (unsigned char*)d_ws;
    u16* qh   = (u16*)(ws);
    u16* ql   = (u16*)(ws + ((size_t)2 << 20));
    u16* kh   = (u16*)(ws + ((size_t)4 << 20));
    u16* kl   = (u16*)(ws + ((size_t)6 << 20));
    u16* vbf  = (u16*)(ws + ((size_t)8 << 20));
    float* zinv = (float*)(ws + ((size_t)24 << 20));
    u16* wvb  = (u16*)(ws + ((size_t)24 << 20) + 0x40000);

    k_cast_wv<<<dim3(256), dim3(256), 0, stream>>>(wv, wvb);
    k_proj_qk<<<dim3(8, 64), dim3(256), 0, stream>>>(x, wq, bq, wk, bk, qh, ql, kh, kl);
    k_proj_v<<<dim3(8, 64), dim3(256), 0, stream>>>(x, wvb, bv, vbf);
    k_zsum<<<dim3(8, 64), dim3(256), 0, stream>>>(qh, ql, kh, kl, zinv);
    k_attn2<<<dim3(8, 64), dim3(256), 0, stream>>>(x, qh, ql, kh, kl, vbf, zinv, gamma, out, amap);
}

// Round 6
// 316.330 us; speedup vs baseline: 4.1555x; 1.9592x over previous
//
#include <hip/hip_runtime.h>

#define B 8
#define C 256
#define NN 4096

typedef float f32x4 __attribute__((ext_vector_type(4)));
typedef short s16x8 __attribute__((ext_vector_type(8)));
typedef unsigned short u16;
typedef unsigned int u32;

__device__ __forceinline__ u16 f2bf(float f) {
    u32 u = __builtin_bit_cast(u32, f);
    u32 r = (u + 0x7fffu + ((u >> 16) & 1u)) >> 16;
    return (u16)r;
}
__device__ __forceinline__ float bf2f(u16 h) {
    u32 u = ((u32)h) << 16;
    return __builtin_bit_cast(float, u);
}

#define MFMA(a, b, c) __builtin_amdgcn_mfma_f32_16x16x32_bf16((a), (b), (c), 0, 0, 0)

// Validated convention (k_st1): D[r]@(lan,g) = sum_d A[g*4+r][d] * B[lan][d].
// Transposed-score: A = Q (rows n), B = K (rows m) -> lane holds m = mbase+lan,
// rows r = 4 consecutive n. Used IDENTICALLY in k_zsum and k_attn2.
__device__ __forceinline__ f32x4 score_mfma_t(s16x8 aqh, s16x8 aql, s16x8 bkh, s16x8 bkl) {
    f32x4 s = {0.f, 0.f, 0.f, 0.f};
    s = MFMA(aqh, bkl, s);
    s = MFMA(aql, bkh, s);
    s = MFMA(aqh, bkh, s);
    return s;
}

__global__ void k_sentinel(float* __restrict__ out, float v) { out[0] = v; }

// ---------------- wv -> bf16 cast ----------------
__global__ void k_cast_wv(const float* __restrict__ wv, u16* __restrict__ wvb) {
    int i = blockIdx.x * 256 + threadIdx.x;
    wvb[i] = f2bf(wv[i]);
}

// ------- q,k projection: coalesced x, LDS-staged weights (broadcast reads) -------
__global__ __launch_bounds__(256) void k_proj_qk(
    const float* __restrict__ x, const float* __restrict__ wq, const float* __restrict__ bq,
    const float* __restrict__ wk, const float* __restrict__ bk,
    u16* __restrict__ qh, u16* __restrict__ ql, u16* __restrict__ kh, u16* __restrict__ kl)
{
    __shared__ float swq[32][64];
    __shared__ float swk[32][64];
    __shared__ u32 sq[64][36];
    __shared__ u32 sk[64][36];
    int t = threadIdx.x;
    int w = t >> 6, l = t & 63;
    int b = blockIdx.x, ng = blockIdx.y;
    int n0 = ng * 64;

    float aq[8], ak[8];
#pragma unroll
    for (int i = 0; i < 8; i++) { aq[i] = bq[w * 8 + i]; ak[i] = bk[w * 8 + i]; }

    const float* xp = x + (size_t)b * C * NN + n0 + l;
    int sd = t >> 3, sc = (t & 7) * 8;  // weight-staging coords
    for (int cc = 0; cc < 4; cc++) {
        __syncthreads();
        *(f32x4*)&swq[sd][sc]     = *(const f32x4*)&wq[sd * C + cc * 64 + sc];
        *(f32x4*)&swq[sd][sc + 4] = *(const f32x4*)&wq[sd * C + cc * 64 + sc + 4];
        *(f32x4*)&swk[sd][sc]     = *(const f32x4*)&wk[sd * C + cc * 64 + sc];
        *(f32x4*)&swk[sd][sc + 4] = *(const f32x4*)&wk[sd * C + cc * 64 + sc + 4];
        __syncthreads();
        for (int c = 0; c < 64; c++) {
            float xv = xp[(size_t)(cc * 64 + c) * NN];
#pragma unroll
            for (int i = 0; i < 8; i++) {
                aq[i] += swq[w * 8 + i][c] * xv;  // wave-uniform -> LDS broadcast
                ak[i] += swk[w * 8 + i][c] * xv;
            }
        }
    }
    __syncthreads();
#pragma unroll
    for (int i = 0; i < 8; i++) {
        u16 qhi = f2bf(aq[i]); u16 qlo = f2bf(aq[i] - bf2f(qhi));
        u16 khi = f2bf(ak[i]); u16 klo = f2bf(ak[i] - bf2f(khi));
        sq[l][w * 8 + i] = ((u32)qhi << 16) | qlo;
        sk[l][w * 8 + i] = ((u32)khi << 16) | klo;
    }
    __syncthreads();
    int nloc = t >> 2, dc = t & 3;
    size_t base = ((size_t)b * NN + n0 + nloc) * 32 + dc * 8;
    uint4 a0 = *(const uint4*)&sq[nloc][dc * 8];
    uint4 a1 = *(const uint4*)&sq[nloc][dc * 8 + 4];
    uint4 b0 = *(const uint4*)&sk[nloc][dc * 8];
    uint4 b1 = *(const uint4*)&sk[nloc][dc * 8 + 4];
    s16x8 vqh, vql, vkh, vkl;
    u32 qa[8] = {a0.x, a0.y, a0.z, a0.w, a1.x, a1.y, a1.z, a1.w};
    u32 ka[8] = {b0.x, b0.y, b0.z, b0.w, b1.x, b1.y, b1.z, b1.w};
#pragma unroll
    for (int i = 0; i < 8; i++) {
        vqh[i] = (short)(qa[i] >> 16); vql[i] = (short)(qa[i] & 0xffff);
        vkh[i] = (short)(ka[i] >> 16); vkl[i] = (short)(ka[i] & 0xffff);
    }
    *(s16x8*)&qh[base] = vqh;
    *(s16x8*)&ql[base] = vql;
    *(s16x8*)&kh[base] = vkh;
    *(s16x8*)&kl[base] = vkl;
}

// ------- v projection, bf16 MFMA (validated convention, unchanged) -------
__global__ __launch_bounds__(256) void k_proj_v(
    const float* __restrict__ x, const u16* __restrict__ wvb, const float* __restrict__ bv,
    u16* __restrict__ vbf)
{
    __shared__ u16 smx[64 * 264];
    int t = threadIdx.x;
    int w = t >> 6, l = t & 63;
    int lan = l & 15, g = l >> 4;
    int b = blockIdx.x, nblk = blockIdx.y;
    int n0 = nblk * 64;
#pragma unroll
    for (int p = 0; p < 16; p++) {
        int flat4 = t + p * 256;
        int c = flat4 >> 4, n4 = (flat4 & 15) * 4;
        float4 xv = *(const float4*)&x[((size_t)b * C + c) * NN + n0 + n4];
        smx[(n4 + 0) * 264 + c] = f2bf(xv.x);
        smx[(n4 + 1) * 264 + c] = f2bf(xv.y);
        smx[(n4 + 2) * 264 + c] = f2bf(xv.z);
        smx[(n4 + 3) * 264 + c] = f2bf(xv.w);
    }
    __syncthreads();
    f32x4 acc[16];
#pragma unroll
    for (int es = 0; es < 16; es++) acc[es] = {0.f, 0.f, 0.f, 0.f};
    int nrow = w * 16 + lan;
    for (int ck = 0; ck < 8; ck++) {
        int c0 = ck * 32 + g * 8;
        s16x8 bfrag = *(const s16x8*)&smx[nrow * 264 + c0];
#pragma unroll
        for (int es = 0; es < 16; es++) {
            s16x8 afrag = *(const s16x8*)&wvb[(size_t)(es * 16 + lan) * 256 + c0];
            acc[es] = MFMA(afrag, bfrag, acc[es]);
        }
    }
    int ncol = n0 + w * 16 + lan;
#pragma unroll
    for (int es = 0; es < 16; es++)
#pragma unroll
        for (int r = 0; r < 4; r++) {
            int e = es * 16 + g * 4 + r;
            vbf[((size_t)b * C + e) * NN + ncol] = f2bf(acc[es][r] + bv[e]);
        }
}

// ------- phase 1: Z sums, transposed scores (lane-local m rows) -------
__global__ __launch_bounds__(256) void k_zsum(
    const u16* __restrict__ qh, const u16* __restrict__ ql,
    const u16* __restrict__ kh, const u16* __restrict__ kl,
    float* __restrict__ zinv)
{
    __shared__ float lZ[4][64];
    int t = threadIdx.x;
    int w = t >> 6, l = t & 63;
    int lan = l & 15, g = l >> 4;
    int b = blockIdx.x, mblk = blockIdx.y;
    int m0 = mblk * 64;

    s16x8 bkh[4], bkl[4];
#pragma unroll
    for (int ms = 0; ms < 4; ms++) {
        size_t ko = ((size_t)b * NN + m0 + ms * 16 + lan) * 32 + g * 8;
        bkh[ms] = *(const s16x8*)&kh[ko];
        bkl[ms] = *(const s16x8*)&kl[ko];
    }
    float zacc[4] = {0.f, 0.f, 0.f, 0.f};
    for (int ci = 0; ci < 64; ci++) {
        int nt = ci * 4 + w;
        size_t qo = ((size_t)b * NN + nt * 16 + lan) * 32 + g * 8;
        s16x8 aqh = *(const s16x8*)&qh[qo];
        s16x8 aql = *(const s16x8*)&ql[qo];
#pragma unroll
        for (int ms = 0; ms < 4; ms++) {
            f32x4 s = score_mfma_t(aqh, aql, bkh[ms], bkl[ms]);
            zacc[ms] += __expf(s[0]) + __expf(s[1]) + __expf(s[2]) + __expf(s[3]);
        }
    }
#pragma unroll
    for (int ms = 0; ms < 4; ms++) {
        float v = zacc[ms];
        v += __shfl_xor(v, 16);
        v += __shfl_xor(v, 32);
        zacc[ms] = v;
    }
    if (g == 0) {
#pragma unroll
        for (int ms = 0; ms < 4; ms++) lZ[w][ms * 16 + lan] = zacc[ms];
    }
    __syncthreads();
    if (t < 64) {
        float Z = lZ[0][t] + lZ[1][t] + lZ[2][t] + lZ[3][t];
        zinv[(size_t)b * NN + m0 + t] = 1.0f / Z;
    }
}

// ------- phase 2: scores -> sma(f32) -> coalesced nt amap store + PV + epilogue -------
__global__ __launch_bounds__(256, 2) void k_attn2(
    const float* __restrict__ x,
    const u16* __restrict__ qh, const u16* __restrict__ ql,
    const u16* __restrict__ kh, const u16* __restrict__ kl,
    const u16* __restrict__ vbf, const float* __restrict__ zinv,
    const float* __restrict__ gamma,
    float* __restrict__ out, float* __restrict__ amap)
{
    __shared__ u16 smv[16384];     // V tile [256 c][64 m], chunk-XOR-swizzled
    __shared__ float sma[64 * 68]; // A tile [64 m][68-pad n] fp32
    int t = threadIdx.x;
    int w = t >> 6, l = t & 63;
    int lan = l & 15, g = l >> 4;
    int b = blockIdx.x, nblk = blockIdx.y;
    int n0 = nblk * 64;
    int nw = n0 + w * 16;

    size_t qo = ((size_t)b * NN + nw + lan) * 32 + g * 8;
    s16x8 aqh = *(const s16x8*)&qh[qo];
    s16x8 aql = *(const s16x8*)&ql[qo];

    f32x4 acc[16];
#pragma unroll
    for (int cs = 0; cs < 16; cs++) acc[cs] = {0.f, 0.f, 0.f, 0.f};
    const u16* vb = vbf + (size_t)b * C * NN;
    const float* ziv = zinv + (size_t)b * NN;
    float* amp = amap + (size_t)b * NN * NN;

    // prologue: stage V tile 0
    s16x8 vreg[8];
#pragma unroll
    for (int p = 0; p < 8; p++) {
        int f8 = t + p * 256; int c = f8 >> 3, j = f8 & 7;
        vreg[p] = *(const s16x8*)&vb[(size_t)c * NN + j * 8];
    }
#pragma unroll
    for (int p = 0; p < 8; p++) {
        int f8 = t + p * 256; int c = f8 >> 3, j = f8 & 7;
        *(s16x8*)&smv[c * 64 + ((j ^ (c & 7)) * 8)] = vreg[p];
    }
    __syncthreads();

    int mloc = t >> 4;       // for amap store phase
    int cb = (t & 15) * 4;

    for (int mstep = 0; mstep < 64; mstep++) {
        int m0 = mstep * 64;
        // T14: issue next V tile's global loads now; ds-write after barrier 2
        if (mstep < 63) {
#pragma unroll
            for (int p = 0; p < 8; p++) {
                int f8 = t + p * 256; int c = f8 >> 3, j = f8 & 7;
                vreg[p] = *(const s16x8*)&vb[(size_t)c * NN + m0 + 64 + j * 8];
            }
        }
        // scores: lane owns m = m0+ms*16+lan, 4 consecutive n = nw+g*4+r -> sma
#pragma unroll
        for (int ms = 0; ms < 4; ms++) {
            size_t ko = ((size_t)b * NN + m0 + ms * 16 + lan) * 32 + g * 8;
            s16x8 fkh = *(const s16x8*)&kh[ko];
            s16x8 fkl = *(const s16x8*)&kl[ko];
            f32x4 s = score_mfma_t(aqh, aql, fkh, fkl);
            float zi = ziv[m0 + ms * 16 + lan];
            f32x4 av;
#pragma unroll
            for (int r = 0; r < 4; r++) av[r] = __expf(s[r]) * zi;
            *(f32x4*)&sma[(ms * 16 + lan) * 68 + w * 16 + g * 4] = av;
        }
        __syncthreads();
        // amap store: 4 rows x 256B fully contiguous per wave-instruction, nontemporal
#pragma unroll
        for (int it = 0; it < 4; it++) {
            int mm = it * 16 + mloc;
            f32x4 v = *(const f32x4*)&sma[mm * 68 + cb];
            __builtin_nontemporal_store(v, (f32x4*)&amp[(size_t)(m0 + mm) * NN + n0 + cb]);
        }
        // PV: acc[cs] (c = cs*16+g*4+r, n = nw+lan) += V[c][m] * A[m][n]
#pragma unroll
        for (int ks = 0; ks < 2; ks++) {
            s16x8 bfrag;
#pragma unroll
            for (int e = 0; e < 8; e++)
                bfrag[e] = (short)f2bf(sma[(ks * 32 + g * 8 + e) * 68 + w * 16 + lan]);
#pragma unroll
            for (int cs = 0; cs < 16; cs++) {
                int row = cs * 16 + lan;
                s16x8 afrag = *(const s16x8*)&smv[row * 64 + (((ks * 4 + g) ^ (lan & 7)) * 8)];
                acc[cs] = MFMA(afrag, bfrag, acc[cs]);
            }
        }
        __syncthreads();
        if (mstep < 63) {
#pragma unroll
            for (int p = 0; p < 8; p++) {
                int f8 = t + p * 256; int c = f8 >> 3, j = f8 & 7;
                *(s16x8*)&smv[c * 64 + ((j ^ (c & 7)) * 8)] = vreg[p];
            }
        }
        // (no 3rd barrier: next iter's score phase doesn't touch smv/sma readers;
        //  barrier after scores orders these smv writes before next PV reads)
    }
    float gm = gamma[0];
    int ncol = nw + lan;
#pragma unroll
    for (int cs = 0; cs < 16; cs++)
#pragma unroll
        for (int r = 0; r < 4; r++) {
            int c = cs * 16 + g * 4 + r;
            size_t oi = ((size_t)b * C + c) * NN + ncol;
            out[oi] = gm * acc[cs][r] + x[oi];
        }
}

extern "C" void kernel_launch(void* const* d_in, const int* in_sizes, int n_in,
                              void* d_out, int out_size, void* d_ws, size_t ws_size,
                              hipStream_t stream) {
    const float* x     = (const float*)d_in[0];
    const float* wq    = (const float*)d_in[1];
    const float* bq    = (const float*)d_in[2];
    const float* wk    = (const float*)d_in[3];
    const float* bk    = (const float*)d_in[4];
    const float* wv    = (const float*)d_in[5];
    const float* bv    = (const float*)d_in[6];
    const float* gamma = (const float*)d_in[7];
    float* out  = (float*)d_out;
    float* amap = out + (size_t)B * C * NN;

    const size_t WS_NEED = (size_t)26 << 20;
    if (ws_size < WS_NEED) {
        k_sentinel<<<dim3(1), dim3(1), 0, stream>>>(out, 8.0e7f);
        return;
    }
    if (n_in < 8 || in_sizes[0] != B * C * NN || in_sizes[1] != 32 * C ||
        in_sizes[2] != 32 || in_sizes[3] != 32 * C || in_sizes[4] != 32 ||
        in_sizes[5] != C * C || in_sizes[6] != C || in_sizes[7] != 1) {
        k_sentinel<<<dim3(1), dim3(1), 0, stream>>>(out, 9.0e7f);
        return;
    }

    unsigned char* ws = (unsigned char*)d_ws;
    u16* qh   = (u16*)(ws);
    u16* ql   = (u16*)(ws + ((size_t)2 << 20));
    u16* kh   = (u16*)(ws + ((size_t)4 << 20));
    u16* kl   = (u16*)(ws + ((size_t)6 << 20));
    u16* vbf  = (u16*)(ws + ((size_t)8 << 20));
    float* zinv = (float*)(ws + ((size_t)24 << 20));
    u16* wvb  = (u16*)(ws + ((size_t)24 << 20) + 0x40000);

    k_cast_wv<<<dim3(256), dim3(256), 0, stream>>>(wv, wvb);
    k_proj_qk<<<dim3(8, 64), dim3(256), 0, stream>>>(x, wq, bq, wk, bk, qh, ql, kh, kl);
    k_proj_v<<<dim3(8, 64), dim3(256), 0, stream>>>(x, wvb, bv, vbf);
    k_zsum<<<dim3(8, 64), dim3(256), 0, stream>>>(qh, ql, kh, kl, zinv);
    k_attn2<<<dim3(8, 64), dim3(256), 0, stream>>>(x, qh, ql, kh, kl, vbf, zinv, gamma, out, amap);
}